// Round 6
// baseline (527.036 us; speedup 1.0000x reference)
//
#include <hip/hip_runtime.h>
#include <stdint.h>

#define TT 300
#define DD 40
#define XROW 72    // halfwords per Xbuf row (64 data + 8 skew) -> 16B-aligned rows
#define HROW 136   // halfwords per Hbuf row (128 data + 8 skew) -> 16B-aligned rows

typedef __attribute__((ext_vector_type(8))) short short8;
typedef __attribute__((ext_vector_type(4))) float f32x4;

// Recurrence buffers and head buffers alias (head runs strictly after the loop).
union SMemU {
  struct {
    ushort Xbuf[2][16 * XROW];   // bf16 x_t rows 0..7 (k 0..39 data, rest 0)
    ushort Hbuf[2][16 * HROW];   // bf16 h: k=2u -> hi, 2u+1 -> lo (rows 8..15 zero)
  } s;                           // 13312 B
  struct {
    float lg[8 * 512];           // 16384 B logits
    float d1t[128 * 8];          // 4096 B dense1 out, [k][s]
    float hbuf[8 * 64];          // 2048 B final h
  } h;                           // 22528 B
};

__device__ __forceinline__ ushort f2bf(float f) {
  uint32_t b = __float_as_uint(f);
  b += 0x7FFFu + ((b >> 16) & 1u);   // RNE
  return (ushort)(b >> 16);
}
__device__ __forceinline__ float bf2f(ushort h) {
  return __uint_as_float((uint32_t)h << 16);
}
__device__ __forceinline__ float sigm(float x) {
  return __builtin_amdgcn_rcpf(1.0f + __expf(-x));
}
__device__ __forceinline__ float tanh_f(float x) {
  return 1.0f - 2.0f * __builtin_amdgcn_rcpf(1.0f + __expf(2.0f * x));
}
// barrier WITHOUT vmcnt drain (keeps x-prefetch ring in flight)
__device__ __forceinline__ void block_sync_lds() {
  asm volatile("s_waitcnt lgkmcnt(0)" ::: "memory");
  __builtin_amdgcn_s_barrier();
}

// Column map: wave w, frag g, col n  <->  gate g of unit u = 16w + n
// => lane L holds acc[g][r] = gate g, unit 16w+(L&15), sample 4*(L>>4)+r
// K map: kt0,1 = x (k<40 real, rest zero); Hbuf k: 2u=h_hi, 2u+1=h_lo,
//        both mapped to W row 40+u (h = hi + lo reconstitutes ~fp32 h).
__global__ __launch_bounds__(256, 1) void lstm_fused_kernel(
    const float* __restrict__ X, const int* __restrict__ seqlen,
    const float* __restrict__ Wk, const float* __restrict__ bias,
    const float* __restrict__ W1, const float* __restrict__ b1,
    const float* __restrict__ gamma, const float* __restrict__ beta,
    const float* __restrict__ mmean, const float* __restrict__ mvar,
    const float* __restrict__ W2, const float* __restrict__ b2,
    float* __restrict__ out)
{
  __shared__ SMemU sm;
  const int tid = threadIdx.x;
  const int wv = tid >> 6, lane = tid & 63;
  const int q = lane >> 4, n16 = lane & 15;
  const int s0 = blockIdx.x * 8;

  // ---- zero X/H buffers (rows 8..15 and pads stay zero forever) ----
  {
    ushort* xz = &sm.s.Xbuf[0][0];
    for (int i = tid; i < 2 * 16 * XROW; i += 256) xz[i] = 0;
    ushort* hz = &sm.s.Hbuf[0][0];
    for (int i = tid; i < 2 * 16 * HROW; i += 256) hz[i] = 0;
  }
  __syncthreads();   // zero-fill visible before x staging below

  // ---- B fragments straight from global; no LDS copy exists -> must stay in regs ----
  const int u = 16 * wv + n16;
  const int kbase = q * 8;
  short8 Bx[2][4], Bh[4][4];
  #pragma unroll
  for (int kt = 0; kt < 2; ++kt)
    #pragma unroll
    for (int g = 0; g < 4; ++g) {
      short8 v;
      #pragma unroll
      for (int j = 0; j < 8; ++j) {
        int k = kt * 32 + kbase + j;
        v[j] = (short)((k < DD) ? f2bf(Wk[k * 256 + g * 64 + u]) : 0);
      }
      Bx[kt][g] = v;
    }
  #pragma unroll
  for (int kt = 0; kt < 4; ++kt)
    #pragma unroll
    for (int g = 0; g < 4; ++g) {
      short8 v;
      #pragma unroll
      for (int j = 0; j < 8; ++j) {
        int kh = kt * 32 + kbase + j;
        v[j] = (short)f2bf(Wk[(DD + (kh >> 1)) * 256 + g * 64 + u]);
      }
      Bh[kt][g] = v;
    }

  // ---- per-lane activation state: 4 samples (4q..4q+3), unit u; lanes<32 real ----
  const float bi = bias[u], bj = bias[64 + u];
  const float bf1 = bias[128 + u] + 1.0f, bo = bias[192 + u];
  int ls[4];
  #pragma unroll
  for (int r = 0; r < 4; ++r) ls[r] = seqlen[s0 + ((4 * q + r) & 7)];

  int ml = seqlen[s0 + (lane & 7)];
  #pragma unroll
  for (int off = 1; off < 64; off <<= 1) ml = max(ml, __shfl_xor(ml, off));
  ml = __builtin_amdgcn_readfirstlane(ml);

  // ---- x loaders: 320 cells = 8 samples x 40 dims ----
  // LOADER FIX: primary strip i = tid (all 256 threads, samples 0..6),
  // secondary strip i = 256 + tid for tid < 64 (wave 0: sample 6 tail + sample 7).
  const int iA = tid, iB = 256 + tid;
  const int sA = (iA * 205) >> 13, dA = iA - sA * 40;
  const int sB = (iB * 205) >> 13, dB = iB - sB * 40;
  const bool hasB = (tid < 64);
  const float* xpA = X + (size_t)(s0 + sA) * (TT * DD) + dA;
  const float* xpB = X + (size_t)(s0 + sB) * (TT * DD) + dB;
  float xrA[4], xrB[4];
  {
    sm.s.Xbuf[0][sA * XROW + dA] = f2bf(xpA[0]);       // x_0
    sm.s.Xbuf[1][sA * XROW + dA] = f2bf(xpA[DD]);      // x_1
    #pragma unroll
    for (int j = 0; j < 4; ++j) xrA[(2 + j) & 3] = xpA[(2 + j) * DD];  // x_2..x_5
    if (hasB) {
      sm.s.Xbuf[0][sB * XROW + dB] = f2bf(xpB[0]);
      sm.s.Xbuf[1][sB * XROW + dB] = f2bf(xpB[DD]);
      #pragma unroll
      for (int j = 0; j < 4; ++j) xrB[(2 + j) & 3] = xpB[(2 + j) * DD];
    }
  }
  __syncthreads();

  // ---- prologue: x-part of z_0 ----
  f32x4 accx[4];
  {
    short8 ax0 = *reinterpret_cast<const short8*>(&sm.s.Xbuf[0][n16 * XROW + kbase]);
    short8 ax1 = *reinterpret_cast<const short8*>(&sm.s.Xbuf[0][n16 * XROW + 32 + kbase]);
    #pragma unroll
    for (int g = 0; g < 4; ++g) {
      f32x4 z4 = {0.f, 0.f, 0.f, 0.f};
      z4 = __builtin_amdgcn_mfma_f32_16x16x32_bf16(ax0, Bx[0][g], z4, 0, 0, 0);
      z4 = __builtin_amdgcn_mfma_f32_16x16x32_bf16(ax1, Bx[1][g], z4, 0, 0, 0);
      accx[g] = z4;
    }
  }
  __syncthreads();   // prologue Xbuf[0] reads done before step 0 writes x_2 there

  float cs[4] = {0.f, 0.f, 0.f, 0.f}, hf[4] = {0.f, 0.f, 0.f, 0.f};

  for (int t = 0; t < ml; ++t) {
    // h_{t-1} fragments (Hbuf[(t+1)&1]; zeros at t=0)
    const ushort* Hb = &sm.s.Hbuf[(t + 1) & 1][0];
    short8 Ah[4];
    #pragma unroll
    for (int kt = 0; kt < 4; ++kt)
      Ah[kt] = *reinterpret_cast<const short8*>(&Hb[n16 * HROW + kt * 32 + kbase]);

    f32x4 acc[4];
    #pragma unroll
    for (int g = 0; g < 4; ++g) acc[g] = accx[g];
    #pragma unroll
    for (int kt = 0; kt < 4; ++kt)
      #pragma unroll
      for (int g = 0; g < 4; ++g)
        acc[g] = __builtin_amdgcn_mfma_f32_16x16x32_bf16(Ah[kt], Bh[kt][g], acc[g], 0, 0, 0);

    // x-part for step t+1 (independent of h -> overlaps activations in the pipe)
    const ushort* Xb = &sm.s.Xbuf[(t + 1) & 1][0];
    short8 ax0 = *reinterpret_cast<const short8*>(&Xb[n16 * XROW + kbase]);
    short8 ax1 = *reinterpret_cast<const short8*>(&Xb[n16 * XROW + 32 + kbase]);
    #pragma unroll
    for (int g = 0; g < 4; ++g) {
      f32x4 z4 = {0.f, 0.f, 0.f, 0.f};
      z4 = __builtin_amdgcn_mfma_f32_16x16x32_bf16(ax0, Bx[0][g], z4, 0, 0, 0);
      z4 = __builtin_amdgcn_mfma_f32_16x16x32_bf16(ax1, Bx[1][g], z4, 0, 0, 0);
      accx[g] = z4;
    }

    // activations fully in-register (lanes 0..31 hold samples 0..7)
    ushort* Hw = &sm.s.Hbuf[t & 1][0];
    if (lane < 32) {
      #pragma unroll
      for (int r = 0; r < 4; ++r) {
        float zi = acc[0][r] + bi, zj = acc[1][r] + bj;
        float zf = acc[2][r] + bf1, zo = acc[3][r] + bo;
        float nc = cs[r] * sigm(zf) + sigm(zi) * tanh_f(zj);
        float nh = tanh_f(nc) * sigm(zo);
        cs[r] = nc;
        if (t == ls[r] - 1) hf[r] = nh;
        ushort hh = f2bf(nh);
        ushort hl = f2bf(nh - bf2f(hh));
        ushort2 hv; hv.x = hh; hv.y = hl;
        *reinterpret_cast<ushort2*>(&Hw[(4 * q + r) * HROW + 2 * u]) = hv;
      }
    }
    // stage x_{t+2}, refill rings with x_{t+6}
    {
      if (t + 2 < TT) {
        sm.s.Xbuf[t & 1][sA * XROW + dA] = f2bf(xrA[(t + 2) & 3]);
        if (hasB) sm.s.Xbuf[t & 1][sB * XROW + dB] = f2bf(xrB[(t + 2) & 3]);
      }
      float nvA = 0.f, nvB = 0.f;
      if (t + 6 < TT) {
        nvA = xpA[(t + 6) * DD];
        if (hasB) nvB = xpB[(t + 6) * DD];
      }
      xrA[(t + 2) & 3] = nvA;
      if (hasB) xrB[(t + 2) & 3] = nvB;
    }
    block_sync_lds();
  }

  // ---- fused head ----
  if (lane < 32) {
    #pragma unroll
    for (int r = 0; r < 4; ++r) sm.h.hbuf[(4 * q + r) * 64 + u] = hf[r];
  }
  __syncthreads();

  { // dense1 + BN + ReLU: j = tid&127, sg = tid>>7 -> samples sg+2r
    const int j = tid & 127, sg = tid >> 7;
    float a[4];
    const float bb = b1[j];
    #pragma unroll
    for (int r = 0; r < 4; ++r) a[r] = bb;
    for (int k = 0; k < 64; ++k) {
      float w = W1[k * 128 + j];
      #pragma unroll
      for (int r = 0; r < 4; ++r)
        a[r] = fmaf(sm.h.hbuf[(sg + 2 * r) * 64 + k], w, a[r]);
    }
    const float ga = gamma[j], be = beta[j], mm = mmean[j];
    const float iv = rsqrtf(mvar[j] + 1e-3f);
    #pragma unroll
    for (int r = 0; r < 4; ++r) {
      float v = fmaxf(a[r], 0.f);
      sm.h.d1t[j * 8 + sg + 2 * r] = ga * (v - mm) * iv + be;
    }
  }
  __syncthreads();

  { // logits: thread owns cols 2tid, 2tid+1 for all 8 samples
    const int cA = tid * 2;
    float ax[8], ay[8];
    const float bA = b2[cA], bB = b2[cA + 1];
    #pragma unroll
    for (int s = 0; s < 8; ++s) { ax[s] = bA; ay[s] = bB; }
    #pragma unroll 4
    for (int k = 0; k < 128; ++k) {
      const float2 w = *reinterpret_cast<const float2*>(&W2[k * 512 + cA]);
      const f32x4 d0 = *reinterpret_cast<const f32x4*>(&sm.h.d1t[k * 8]);
      const f32x4 d1 = *reinterpret_cast<const f32x4*>(&sm.h.d1t[k * 8 + 4]);
      #pragma unroll
      for (int s = 0; s < 4; ++s) {
        ax[s]     = fmaf(d0[s], w.x, ax[s]);  ay[s]     = fmaf(d0[s], w.y, ay[s]);
        ax[s + 4] = fmaf(d1[s], w.x, ax[s + 4]); ay[s + 4] = fmaf(d1[s], w.y, ay[s + 4]);
      }
    }
    #pragma unroll
    for (int s = 0; s < 8; ++s) {
      float2 lw; lw.x = ax[s]; lw.y = ay[s];
      *reinterpret_cast<float2*>(&sm.h.lg[s * 512 + cA]) = lw;
    }
  }
  __syncthreads();

  { // softmax: wave wv handles samples wv and wv+4
    #pragma unroll
    for (int si = 0; si < 2; ++si) {
      const int s = wv + 4 * si;
      float v[8];
      float m = -3.4e38f;
      #pragma unroll
      for (int i = 0; i < 8; ++i) {
        v[i] = sm.h.lg[s * 512 + lane + 64 * i];
        m = fmaxf(m, v[i]);
      }
      #pragma unroll
      for (int off = 1; off < 64; off <<= 1) m = fmaxf(m, __shfl_xor(m, off));
      float sum = 0.f;
      #pragma unroll
      for (int i = 0; i < 8; ++i) { v[i] = __expf(v[i] - m); sum += v[i]; }
      #pragma unroll
      for (int off = 1; off < 64; off <<= 1) sum += __shfl_xor(sum, off);
      const float inv = __builtin_amdgcn_rcpf(sum);
      #pragma unroll
      for (int i = 0; i < 8; ++i)
        out[(size_t)(s0 + s) * 512 + lane + 64 * i] = v[i] * inv;
    }
  }
}

extern "C" void kernel_launch(void* const* d_in, const int* in_sizes, int n_in,
                              void* d_out, int out_size, void* d_ws, size_t ws_size,
                              hipStream_t stream) {
  const float* X      = (const float*)d_in[0];
  const int*   seqlen = (const int*)d_in[1];
  const float* Wk     = (const float*)d_in[2];
  const float* bias   = (const float*)d_in[3];
  const float* W1     = (const float*)d_in[4];
  const float* b1     = (const float*)d_in[5];
  const float* gam    = (const float*)d_in[6];
  const float* bet    = (const float*)d_in[7];
  const float* mmean  = (const float*)d_in[8];
  const float* mvar   = (const float*)d_in[9];
  const float* W2     = (const float*)d_in[10];
  const float* b2     = (const float*)d_in[11];
  float* out = (float*)d_out;

  lstm_fused_kernel<<<dim3(256), dim3(256), 0, stream>>>(
      X, seqlen, Wk, bias, W1, b1, gam, bet, mmean, mvar, W2, b2, out);
}

// Round 7
// 504.767 us; speedup vs baseline: 1.0441x; 1.0441x over previous
//
#include <hip/hip_runtime.h>
#include <stdint.h>

#define TT 300
#define DD 40
#define XROW 72    // halfwords per Xbuf row (64 data + 8 skew)
#define HROW 136   // halfwords per Hbuf row (128 data + 8 skew)

typedef __attribute__((ext_vector_type(8))) short short8;
typedef __attribute__((ext_vector_type(4))) float f32x4;

// Recurrence buffers and head buffers alias (head runs strictly after the loop).
union SMemU {
  struct {
    ushort Xbuf[2][16 * XROW];   // bf16 x rows 0..3 (k 0..39 data, rest 0)
    ushort Hbuf[2][16 * HROW];   // bf16 h: k=2u hi, 2u+1 lo (rows 4..15 zero)
  } s;                           // 13312 B
  struct {
    float lg[4 * 512];           // logits
    float d1t[128 * 4];          // dense1 out [k][s]
    float hbuf[4 * 64];          // final h
  } h;
};

__device__ __forceinline__ ushort f2bf(float f) {
  uint32_t b = __float_as_uint(f);
  b += 0x7FFFu + ((b >> 16) & 1u);   // RNE
  return (ushort)(b >> 16);
}
__device__ __forceinline__ float bf2f(ushort h) {
  return __uint_as_float((uint32_t)h << 16);
}
__device__ __forceinline__ float sigm(float x) {
  return __builtin_amdgcn_rcpf(1.0f + __expf(-x));
}
__device__ __forceinline__ float tanh_f(float x) {
  return 1.0f - 2.0f * __builtin_amdgcn_rcpf(1.0f + __expf(2.0f * x));
}
// barrier WITHOUT vmcnt drain (keeps x-prefetch loads in flight)
__device__ __forceinline__ void block_sync_lds() {
  asm volatile("s_waitcnt lgkmcnt(0)" ::: "memory");
  __builtin_amdgcn_s_barrier();
}

// Column map: wave w, frag g, col n <-> gate g of unit u = 16w + n.
// Lane L holds acc[g][r] = gate g, unit 16w+(L&15), sample r (q = L>>4 == 0).
// K map: kt0,1 = x; Hbuf k: 2u = h_hi, 2u+1 = h_lo (both -> W row 40+u).
__global__ __launch_bounds__(256, 2) void lstm_fused_kernel(
    const float* __restrict__ X, const int* __restrict__ seqlen,
    const float* __restrict__ Wk, const float* __restrict__ bias,
    const float* __restrict__ W1, const float* __restrict__ b1,
    const float* __restrict__ gamma, const float* __restrict__ beta,
    const float* __restrict__ mmean, const float* __restrict__ mvar,
    const float* __restrict__ W2, const float* __restrict__ b2,
    float* __restrict__ out)
{
  __shared__ SMemU sm;
  const int tid = threadIdx.x;
  const int wv = tid >> 6, lane = tid & 63;
  const int q = lane >> 4, n16 = lane & 15;
  const int s0 = blockIdx.x * 4;

  // ---- zero X/H buffers ----
  {
    ushort* xz = &sm.s.Xbuf[0][0];
    for (int i = tid; i < 2 * 16 * XROW; i += 256) xz[i] = 0;
    ushort* hz = &sm.s.Hbuf[0][0];
    for (int i = tid; i < 2 * 16 * HROW; i += 256) hz[i] = 0;
  }
  __syncthreads();

  // ---- B fragments straight from global -> registers ----
  const int u = 16 * wv + n16;
  const int kbase = q * 8;
  short8 Bx[2][4], Bh[4][4];
  #pragma unroll
  for (int kt = 0; kt < 2; ++kt)
    #pragma unroll
    for (int g = 0; g < 4; ++g) {
      short8 v;
      #pragma unroll
      for (int j = 0; j < 8; ++j) {
        int k = kt * 32 + kbase + j;
        v[j] = (short)((k < DD) ? f2bf(Wk[k * 256 + g * 64 + u]) : 0);
      }
      Bx[kt][g] = v;
    }
  #pragma unroll
  for (int kt = 0; kt < 4; ++kt)
    #pragma unroll
    for (int g = 0; g < 4; ++g) {
      short8 v;
      #pragma unroll
      for (int j = 0; j < 8; ++j) {
        int kh = kt * 32 + kbase + j;
        v[j] = (short)f2bf(Wk[(DD + (kh >> 1)) * 256 + g * 64 + u]);
      }
      Bh[kt][g] = v;
    }

  const float bi = bias[u], bj = bias[64 + u];
  const float bf1 = bias[128 + u] + 1.0f, bo = bias[192 + u];
  int ls0 = seqlen[s0], ls1 = seqlen[s0 + 1];
  int ls2 = seqlen[s0 + 2], ls3 = seqlen[s0 + 3];
  const int ml = max(max(ls0, ls1), max(ls2, ls3));
  const int mlr = (ml + 1) & ~1;

  // ---- x loaders: 160 cells = 4 samples x 40 dims, single strip ----
  const bool xth = tid < 160;
  int sA = (tid * 205) >> 13; if (sA > 3) sA = 3;
  const int dA = tid - sA * 40;  // only meaningful for xth
  const float* xp = X + (size_t)(s0 + sA) * (TT * DD) + (xth ? dA : 0);
  float e0 = 0.f, e1 = 0.f, e2 = 0.f, e3 = 0.f;
  if (xth) {
    sm.s.Xbuf[0][sA * XROW + dA] = f2bf(xp[0]);       // x_0
    sm.s.Xbuf[1][sA * XROW + dA] = f2bf(xp[DD]);      // x_1
    e0 = xp[2 * DD]; e1 = xp[3 * DD];                 // x_2, x_3
    e2 = xp[4 * DD]; e3 = xp[5 * DD];                 // x_4, x_5
  }
  __syncthreads();

  // ---- prologue: x-part of z_0 from Xbuf[0] ----
  f32x4 accx[4];
  {
    short8 ax0 = *reinterpret_cast<const short8*>(&sm.s.Xbuf[0][n16 * XROW + kbase]);
    short8 ax1 = *reinterpret_cast<const short8*>(&sm.s.Xbuf[0][n16 * XROW + 32 + kbase]);
    #pragma unroll
    for (int g = 0; g < 4; ++g) {
      f32x4 z4 = {0.f, 0.f, 0.f, 0.f};
      z4 = __builtin_amdgcn_mfma_f32_16x16x32_bf16(ax0, Bx[0][g], z4, 0, 0, 0);
      z4 = __builtin_amdgcn_mfma_f32_16x16x32_bf16(ax1, Bx[1][g], z4, 0, 0, 0);
      accx[g] = z4;
    }
  }
  __syncthreads();   // prologue reads done before step 0 stages x_2 into Xbuf[0]

  float cs[4] = {0.f, 0.f, 0.f, 0.f}, hf[4] = {0.f, 0.f, 0.f, 0.f};

  // One half-step; all parities static. Order: h-MFMA -> activations ->
  // h-write + x-stage -> accx MFMA (next step's x-part, off critical path).
  auto halfstep = [&](int t, const ushort* __restrict__ Hrd,
                      ushort* __restrict__ Hwr,
                      const ushort* __restrict__ Xrd,
                      ushort* __restrict__ Xst, float ex) {
    short8 Ah[4];
    #pragma unroll
    for (int kt = 0; kt < 4; ++kt)
      Ah[kt] = *reinterpret_cast<const short8*>(&Hrd[n16 * HROW + kt * 32 + kbase]);

    f32x4 acc[4];
    #pragma unroll
    for (int g = 0; g < 4; ++g)
      acc[g] = __builtin_amdgcn_mfma_f32_16x16x32_bf16(Ah[0], Bh[0][g], accx[g], 0, 0, 0);
    #pragma unroll
    for (int kt = 1; kt < 4; ++kt)
      #pragma unroll
      for (int g = 0; g < 4; ++g)
        acc[g] = __builtin_amdgcn_mfma_f32_16x16x32_bf16(Ah[kt], Bh[kt][g], acc[g], 0, 0, 0);

    if (q == 0) {   // lanes 0..15: samples r=0..3, unit u
      #pragma unroll
      for (int r = 0; r < 4; ++r) {
        float zi = acc[0][r] + bi, zj = acc[1][r] + bj;
        float zf = acc[2][r] + bf1, zo = acc[3][r] + bo;
        float nc = cs[r] * sigm(zf) + sigm(zi) * tanh_f(zj);
        float nh = tanh_f(nc) * sigm(zo);
        cs[r] = nc;
        int lr = (r == 0) ? ls0 : (r == 1) ? ls1 : (r == 2) ? ls2 : ls3;
        if (t == lr - 1) hf[r] = nh;
        ushort hh = f2bf(nh);
        ushort hl = f2bf(nh - bf2f(hh));
        ushort2 hv; hv.x = hh; hv.y = hl;
        *reinterpret_cast<ushort2*>(&Hwr[r * HROW + 2 * u]) = hv;
      }
    }
    if (xth) Xst[sA * XROW + dA] = f2bf(ex);   // stage x_{t+2}

    // x-part of z_{t+1} from Xrd (x_{t+1}); consumed next half-step
    short8 ax0 = *reinterpret_cast<const short8*>(&Xrd[n16 * XROW + kbase]);
    short8 ax1 = *reinterpret_cast<const short8*>(&Xrd[n16 * XROW + 32 + kbase]);
    #pragma unroll
    for (int g = 0; g < 4; ++g) {
      f32x4 z4 = {0.f, 0.f, 0.f, 0.f};
      z4 = __builtin_amdgcn_mfma_f32_16x16x32_bf16(ax0, Bx[0][g], z4, 0, 0, 0);
      z4 = __builtin_amdgcn_mfma_f32_16x16x32_bf16(ax1, Bx[1][g], z4, 0, 0, 0);
      accx[g] = z4;
    }
  };

  for (int t = 0; t < mlr; t += 2) {
    halfstep(t,     sm.s.Hbuf[1], sm.s.Hbuf[0], sm.s.Xbuf[1], sm.s.Xbuf[0], e0);
    block_sync_lds();
    halfstep(t + 1, sm.s.Hbuf[0], sm.s.Hbuf[1], sm.s.Xbuf[0], sm.s.Xbuf[1], e1);
    e0 = e2; e1 = e3;
    if (xth) {
      int i6 = min(t + 6, TT - 1), i7 = min(t + 7, TT - 1);
      e2 = xp[i6 * DD];
      e3 = xp[i7 * DD];
    }
    block_sync_lds();
  }

  // ---- fused head (buffers alias the recurrence LDS; loop fully barriered) ----
  if (q == 0) {
    #pragma unroll
    for (int r = 0; r < 4; ++r) sm.h.hbuf[r * 64 + u] = hf[r];
  }
  __syncthreads();

  { // dense1 + BN + ReLU: j = tid&127, sg = tid>>7 -> samples sg, sg+2
    const int j = tid & 127, sg = tid >> 7;
    float a0 = b1[j], a1 = a0;
    for (int k = 0; k < 64; ++k) {
      float w = W1[k * 128 + j];
      a0 = fmaf(sm.h.hbuf[sg * 64 + k], w, a0);
      a1 = fmaf(sm.h.hbuf[(sg + 2) * 64 + k], w, a1);
    }
    const float ga = gamma[j], be = beta[j], mm = mmean[j];
    const float iv = rsqrtf(mvar[j] + 1e-3f);
    a0 = fmaxf(a0, 0.f); a1 = fmaxf(a1, 0.f);
    sm.h.d1t[j * 4 + sg]     = ga * (a0 - mm) * iv + be;
    sm.h.d1t[j * 4 + sg + 2] = ga * (a1 - mm) * iv + be;
  }
  __syncthreads();

  { // logits: thread owns cols 2tid, 2tid+1 for all 4 samples
    const int cA = tid * 2;
    float ax[4], ay[4];
    const float bA = b2[cA], bB = b2[cA + 1];
    #pragma unroll
    for (int s = 0; s < 4; ++s) { ax[s] = bA; ay[s] = bB; }
    #pragma unroll 4
    for (int k = 0; k < 128; ++k) {
      const float2 w = *reinterpret_cast<const float2*>(&W2[k * 512 + cA]);
      const f32x4 d = *reinterpret_cast<const f32x4*>(&sm.h.d1t[k * 4]);
      #pragma unroll
      for (int s = 0; s < 4; ++s) {
        ax[s] = fmaf(d[s], w.x, ax[s]);
        ay[s] = fmaf(d[s], w.y, ay[s]);
      }
    }
    #pragma unroll
    for (int s = 0; s < 4; ++s) {
      float2 lw; lw.x = ax[s]; lw.y = ay[s];
      *reinterpret_cast<float2*>(&sm.h.lg[s * 512 + cA]) = lw;
    }
  }
  __syncthreads();

  { // softmax: wave wv handles sample wv
    float v[8];
    float m = -3.4e38f;
    #pragma unroll
    for (int i = 0; i < 8; ++i) {
      v[i] = sm.h.lg[wv * 512 + lane + 64 * i];
      m = fmaxf(m, v[i]);
    }
    #pragma unroll
    for (int off = 1; off < 64; off <<= 1) m = fmaxf(m, __shfl_xor(m, off));
    float sum = 0.f;
    #pragma unroll
    for (int i = 0; i < 8; ++i) { v[i] = __expf(v[i] - m); sum += v[i]; }
    #pragma unroll
    for (int off = 1; off < 64; off <<= 1) sum += __shfl_xor(sum, off);
    const float inv = __builtin_amdgcn_rcpf(sum);
    #pragma unroll
    for (int i = 0; i < 8; ++i)
      out[(size_t)(s0 + wv) * 512 + lane + 64 * i] = v[i] * inv;
  }
}

extern "C" void kernel_launch(void* const* d_in, const int* in_sizes, int n_in,
                              void* d_out, int out_size, void* d_ws, size_t ws_size,
                              hipStream_t stream) {
  const float* X      = (const float*)d_in[0];
  const int*   seqlen = (const int*)d_in[1];
  const float* Wk     = (const float*)d_in[2];
  const float* bias   = (const float*)d_in[3];
  const float* W1     = (const float*)d_in[4];
  const float* b1     = (const float*)d_in[5];
  const float* gam    = (const float*)d_in[6];
  const float* bet    = (const float*)d_in[7];
  const float* mmean  = (const float*)d_in[8];
  const float* mvar   = (const float*)d_in[9];
  const float* W2     = (const float*)d_in[10];
  const float* b2     = (const float*)d_in[11];
  float* out = (float*)d_out;

  lstm_fused_kernel<<<dim3(512), dim3(256), 0, stream>>>(
      X, seqlen, Wk, bias, W1, b1, gam, bet, mmean, mvar, W2, b2, out);
}